// Round 4
// baseline (253.217 us; speedup 1.0000x reference)
//
#include <hip/hip_runtime.h>

typedef _Float16 f16x8 __attribute__((ext_vector_type(8)));
typedef unsigned short u16x8v __attribute__((ext_vector_type(8)));
typedef unsigned short u16x4v __attribute__((ext_vector_type(4)));
typedef float f32x4 __attribute__((ext_vector_type(4)));

constexpr int SEQ = 2048;
constexpr int DIM = 1024;
constexpr int BATCH = 4;
constexpr size_t NBS = (size_t)BATCH * SEQ * DIM;  // 8388608

static __device__ __forceinline__ unsigned short f2h(float f) {
    return __builtin_bit_cast(unsigned short, (_Float16)f);  // RNE
}
static __device__ __forceinline__ float h2f(unsigned short u) {
    return (float)__builtin_bit_cast(_Float16, u);
}
static __device__ __forceinline__ f16x8 ldsld(const unsigned short* p) {
    return __builtin_bit_cast(f16x8, *(const u16x8v*)p);
}
// Async global->LDS, 16B/lane. LDS dest = wave-uniform base + lane*16B.
static __device__ __forceinline__ void gld_lds16(const unsigned short* g, unsigned short* l) {
    __builtin_amdgcn_global_load_lds(
        (const __attribute__((address_space(1))) void*)g,
        (__attribute__((address_space(3))) void*)l, 16, 0, 0);
}

// ---------------------------------------------------------------------------
// fp32 -> fp16 convert, X + all 3 W in ONE launch.
// Blocks [0,8192): X. Blocks [8192, 8192+3072): W0..W2.
// ---------------------------------------------------------------------------
__global__ __launch_bounds__(256) void cvt_all(
    const float* __restrict__ X,
    const float* __restrict__ W0, const float* __restrict__ W1,
    const float* __restrict__ W2,
    unsigned short* __restrict__ Xf, unsigned short* __restrict__ Wf)
{
    const int b = blockIdx.x;
    const float* src;
    unsigned short* dst;
    int i;
    if (b < 8192) {
        src = X; dst = Xf;
        i = b * 256 + threadIdx.x;
    } else {
        const int wb = b - 8192;
        const int z = wb >> 10;              // 1024 blocks per weight
        src = (z == 0) ? W0 : (z == 1) ? W1 : W2;
        dst = Wf + (size_t)z * DIM * DIM;
        i = (wb & 1023) * 256 + threadIdx.x;
    }
    float4 f = ((const float4*)src)[i];
    u16x4v h;
    h.x = f2h(f.x); h.y = f2h(f.y); h.z = f2h(f.z); h.w = f2h(f.w);
    ((u16x4v*)dst)[i] = h;
}

// ---------------------------------------------------------------------------
// Fused Q/K/V projection, fp16 MFMA. 128x128 tile, 4 waves x 64x64, BK=64,
// XOR-swizzled LDS (rule 21: linear gld_lds dest + inverse-swizzled global
// source + swizzled read). 1-D grid with bijective XCD chunk swizzle
// (1536 % 8 == 0), m-major decode: each XCD owns a contiguous 8-wide m0
// chunk (2 MB X slice, L2-resident) across all (n0, z).
// ---------------------------------------------------------------------------
__global__ __launch_bounds__(256) void qkv_gemm(
    const unsigned short* __restrict__ Xf, const unsigned short* __restrict__ Wf,
    unsigned short* __restrict__ Qf, unsigned short* __restrict__ Kf,
    unsigned short* __restrict__ Vt)
{
    __shared__ __attribute__((aligned(16))) unsigned short Ah[128 * 64];
    __shared__ __attribute__((aligned(16))) unsigned short Bh[128 * 64];
    const int flat = blockIdx.x;                 // 0..1535
    const int wgid = (flat & 7) * 192 + (flat >> 3);
    const int mt = wgid / 24;                    // 0..63, m-major
    const int rem = wgid - mt * 24;
    const int nt = rem / 3;                      // 0..7
    const int z = rem - nt * 3;                  // 0..2
    const int m0 = mt * 128, n0 = nt * 128;
    const unsigned short* Wz = Wf + (size_t)z * DIM * DIM;
    const int tid = threadIdx.x;
    const int w = tid >> 6, lane = tid & 63, q = lane >> 4, c = lane & 15;
    const int wrow = (w >> 1) * 64, wcol = (w & 1) * 64;
    const int g8 = lane >> 3;                 // row-in-group 0..7
    const int cu = (lane & 7) ^ g8;           // inverse-swizzled col unit
    const int srow = w * 8 + g8;              // staging row (call j adds j*32)
    const int scol = cu * 8;                  // shorts
    unsigned short* lA = Ah + w * 512;        // wave-uniform LDS bases
    unsigned short* lB = Bh + w * 512;
    const int c7 = c & 7;

    f32x4 acc[4][4];
#pragma unroll
    for (int a = 0; a < 4; ++a)
#pragma unroll
        for (int b = 0; b < 4; ++b) acc[a][b] = (f32x4){0.f, 0.f, 0.f, 0.f};

    for (int k0 = 0; k0 < DIM; k0 += 64) {
        __syncthreads();
        {
            const size_t ga = (size_t)(m0 + srow) * DIM + k0 + scol;
            const size_t gb = (size_t)(n0 + srow) * DIM + k0 + scol;
#pragma unroll
            for (int j = 0; j < 4; ++j) {
                gld_lds16(Xf + ga + (size_t)(j * 32) * DIM, lA + j * 2048);
                gld_lds16(Wz + gb + (size_t)(j * 32) * DIM, lB + j * 2048);
            }
        }
        __syncthreads();
#pragma unroll
        for (int kk = 0; kk < 2; ++kk) {
            f16x8 ah[4], bh[4];
#pragma unroll
            for (int mi = 0; mi < 4; ++mi)
                ah[mi] = ldsld(Ah + (wrow + mi * 16 + c) * 64 + (((kk << 2) + q) ^ c7) * 8);
#pragma unroll
            for (int ni = 0; ni < 4; ++ni)
                bh[ni] = ldsld(Bh + (wcol + ni * 16 + c) * 64 + (((kk << 2) + q) ^ c7) * 8);
#pragma unroll
            for (int mi = 0; mi < 4; ++mi)
#pragma unroll
                for (int ni = 0; ni < 4; ++ni)
                    acc[mi][ni] = __builtin_amdgcn_mfma_f32_16x16x32_f16(ah[mi], bh[ni], acc[mi][ni], 0, 0, 0);
        }
    }

    if (z == 2) {
        // V: store transposed Vt[b][d][s], fp16.
#pragma unroll
        for (int mi = 0; mi < 4; ++mi) {
            const int mg = m0 + wrow + mi * 16 + q * 4;
            const int bb = mg >> 11, ss = mg & (SEQ - 1);
#pragma unroll
            for (int ni = 0; ni < 4; ++ni) {
                const int col = n0 + wcol + ni * 16 + c;
                u16x4v v;
                v.x = f2h(acc[mi][ni][0]);
                v.y = f2h(acc[mi][ni][1]);
                v.z = f2h(acc[mi][ni][2]);
                v.w = f2h(acc[mi][ni][3]);
                *(u16x4v*)(Vt + ((size_t)bb * DIM + col) * SEQ + ss) = v;
            }
        }
    } else {
        unsigned short* OH = z ? Kf : Qf;
#pragma unroll
        for (int mi = 0; mi < 4; ++mi)
#pragma unroll
            for (int ni = 0; ni < 4; ++ni) {
                const int col = n0 + wcol + ni * 16 + c;
#pragma unroll
                for (int r = 0; r < 4; ++r) {
                    const int row = m0 + wrow + mi * 16 + q * 4 + r;
                    OH[(size_t)row * DIM + col] = f2h(acc[mi][ni][r]);
                }
            }
    }
}

// ---------------------------------------------------------------------------
// Scores GEMM, ALL batches: S = Qf Kf^T * SCALE, fp16 out. Faithful masking
// of scores==0 on the f32 accumulator: writes 0xFC00. Grid (16,16,BATCH);
// skips tiles above the diagonal. BK=64 swizzled.
// ---------------------------------------------------------------------------
__global__ __launch_bounds__(256) void scores_gemm1b(
    const unsigned short* __restrict__ Q, const unsigned short* __restrict__ K,
    unsigned short* __restrict__ S)
{
    if (blockIdx.y > blockIdx.x) return;
    __shared__ __attribute__((aligned(16))) unsigned short Ah[128 * 64];
    __shared__ __attribute__((aligned(16))) unsigned short Bh[128 * 64];
    const int i0 = blockIdx.x * 128, j0 = blockIdx.y * 128, b = blockIdx.z;
    const unsigned short* Qb = Q + (size_t)b * SEQ * DIM;
    const unsigned short* Kb = K + (size_t)b * SEQ * DIM;
    unsigned short* Sb = S + (size_t)b * SEQ * SEQ;
    const int tid = threadIdx.x;
    const int w = tid >> 6, lane = tid & 63, q = lane >> 4, c = lane & 15;
    const int wrow = (w >> 1) * 64, wcol = (w & 1) * 64;
    const int g8 = lane >> 3;
    const int cu = (lane & 7) ^ g8;
    const int srow = w * 8 + g8;
    const int scol = cu * 8;
    unsigned short* lA = Ah + w * 512;
    unsigned short* lB = Bh + w * 512;
    const int c7 = c & 7;

    f32x4 acc[4][4];
#pragma unroll
    for (int a = 0; a < 4; ++a)
#pragma unroll
        for (int bq = 0; bq < 4; ++bq) acc[a][bq] = (f32x4){0.f, 0.f, 0.f, 0.f};

    for (int k0 = 0; k0 < DIM; k0 += 64) {
        __syncthreads();
        {
            const size_t ga = (size_t)(i0 + srow) * DIM + k0 + scol;
            const size_t gb = (size_t)(j0 + srow) * DIM + k0 + scol;
#pragma unroll
            for (int j = 0; j < 4; ++j) {
                gld_lds16(Qb + ga + (size_t)(j * 32) * DIM, lA + j * 2048);
                gld_lds16(Kb + gb + (size_t)(j * 32) * DIM, lB + j * 2048);
            }
        }
        __syncthreads();
#pragma unroll
        for (int kk = 0; kk < 2; ++kk) {
            f16x8 ah[4], bh[4];
#pragma unroll
            for (int mi = 0; mi < 4; ++mi)
                ah[mi] = ldsld(Ah + (wrow + mi * 16 + c) * 64 + (((kk << 2) + q) ^ c7) * 8);
#pragma unroll
            for (int ni = 0; ni < 4; ++ni)
                bh[ni] = ldsld(Bh + (wcol + ni * 16 + c) * 64 + (((kk << 2) + q) ^ c7) * 8);
#pragma unroll
            for (int mi = 0; mi < 4; ++mi)
#pragma unroll
                for (int ni = 0; ni < 4; ++ni)
                    acc[mi][ni] = __builtin_amdgcn_mfma_f32_16x16x32_f16(ah[mi], bh[ni], acc[mi][ni], 0, 0, 0);
        }
    }
#pragma unroll
    for (int mi = 0; mi < 4; ++mi)
#pragma unroll
        for (int ni = 0; ni < 4; ++ni) {
            const int col = j0 + wcol + ni * 16 + c;
#pragma unroll
            for (int r = 0; r < 4; ++r) {
                const int row = i0 + wrow + mi * 16 + q * 4 + r;
                const float sc = acc[mi][ni][r] * 0.03125f;
                Sb[(size_t)row * SEQ + col] =
                    (sc == 0.f) ? (unsigned short)0xFC00u : f2h(sc);
            }
        }
}

// ---------------------------------------------------------------------------
// Row-wise masked softmax: fp16 S -> fp16 P. j > i masked; scores==0 already
// -inf. Skip loads beyond i, skip writes beyond rowtile end. Grid (SEQ, BATCH).
// ---------------------------------------------------------------------------
__global__ __launch_bounds__(256) void softmax_row_b(
    const unsigned short* __restrict__ S, unsigned short* __restrict__ P)
{
    const int i = blockIdx.x, t = threadIdx.x;
    const size_t ro = ((size_t)blockIdx.y * SEQ + i) * SEQ;
    const int wid = t >> 6, lane = t & 63;
    __shared__ float redm[4], reds[4];
    const int j0 = t * 8;
    const int rti = (i & ~127) + 128;        // pv reads cols < rti only
    float sv[8];
    float mx = -__builtin_inff();
    if (j0 <= i) {
        u16x8v raw = *(const u16x8v*)(S + ro + j0);
#pragma unroll
        for (int u = 0; u < 8; ++u) {
            float s = (j0 + u <= i) ? h2f(raw[u]) : -__builtin_inff();
            sv[u] = s;
            mx = fmaxf(mx, s);
        }
    } else {
#pragma unroll
        for (int u = 0; u < 8; ++u) sv[u] = -__builtin_inff();
    }
#pragma unroll
    for (int off = 1; off < 64; off <<= 1) mx = fmaxf(mx, __shfl_xor(mx, off));
    if (lane == 0) redm[wid] = mx;
    __syncthreads();
    const float M = fmaxf(fmaxf(redm[0], redm[1]), fmaxf(redm[2], redm[3]));
    float sum = 0.f;
#pragma unroll
    for (int u = 0; u < 8; ++u) {
        float e = __expf(sv[u] - M);
        sv[u] = e;
        sum += e;
    }
#pragma unroll
    for (int off = 1; off < 64; off <<= 1) sum += __shfl_xor(sum, off);
    if (lane == 0) reds[wid] = sum;
    __syncthreads();
    const float rinv = 1.f / (reds[0] + reds[1] + reds[2] + reds[3]);
    if (j0 < rti) {
        u16x8v o;
#pragma unroll
        for (int u = 0; u < 8; ++u) o[u] = f2h(sv[u] * rinv);
        *(u16x8v*)(P + ro + j0) = o;
    }
}

// ---------------------------------------------------------------------------
// out = P @ V via Vt (NT MFMA, fp16). 128x128 tile, BK=64 swizzled, k-loop
// truncated at causal bound. Split-K for long tiles (i0 >= 1024): two blocks
// each do half the K-range and atomicAdd fp32 partials into pre-zeroed Out.
// Max K-steps per block: 16 (balanced). Grid x: 0..7 short tiles (store),
// 8..23 long tiles x 2 splits (atomic).
// ---------------------------------------------------------------------------
__global__ __launch_bounds__(256) void pv_gemm(
    const unsigned short* __restrict__ Pm, const unsigned short* __restrict__ Vt,
    float* __restrict__ Out)
{
    __shared__ __attribute__((aligned(16))) unsigned short Ps[128 * 64];
    __shared__ __attribute__((aligned(16))) unsigned short Vs[128 * 64];
    const int xt = blockIdx.x;
    int i0t, ks0, ks1;
    bool useAtomic;
    if (xt < 8) {
        i0t = xt; ks0 = 0; ks1 = 2 * xt + 2; useAtomic = false;
    } else {
        i0t = 8 + ((xt - 8) >> 1);
        const int njs = 2 * i0t + 2;
        const int nh = i0t + 1;              // = (njs+1)/2
        const int s = (xt - 8) & 1;
        ks0 = s ? nh : 0; ks1 = s ? njs : nh;
        useAtomic = true;
    }
    const int i0 = i0t * 128, d0 = blockIdx.y * 128, b = blockIdx.z;
    const int tid = threadIdx.x;
    const int w = tid >> 6, lane = tid & 63, q = lane >> 4, c = lane & 15;
    const int wrow = (w >> 1) * 64, wcol = (w & 1) * 64;
    const int g8 = lane >> 3;
    const int cu = (lane & 7) ^ g8;
    const int srow = w * 8 + g8;
    const int scol = cu * 8;
    unsigned short* lA = Ps + w * 512;
    unsigned short* lB = Vs + w * 512;
    const int c7 = c & 7;

    f32x4 acc[4][4];
#pragma unroll
    for (int a = 0; a < 4; ++a)
#pragma unroll
        for (int bq = 0; bq < 4; ++bq) acc[a][bq] = (f32x4){0.f, 0.f, 0.f, 0.f};

    for (int ks = ks0; ks < ks1; ++ks) {
        const int j0 = ks * 64;
        __syncthreads();
        {
            const size_t gpa = ((size_t)b * SEQ + i0 + srow) * SEQ + j0 + scol;
            const size_t gva = ((size_t)b * DIM + d0 + srow) * SEQ + j0 + scol;
#pragma unroll
            for (int j = 0; j < 4; ++j) {
                gld_lds16(Pm + gpa + (size_t)(j * 32) * SEQ, lA + j * 2048);
                gld_lds16(Vt + gva + (size_t)(j * 32) * SEQ, lB + j * 2048);
            }
        }
        __syncthreads();
#pragma unroll
        for (int kk = 0; kk < 2; ++kk) {
            f16x8 ah[4], bh[4];
#pragma unroll
            for (int mi = 0; mi < 4; ++mi)
                ah[mi] = ldsld(Ps + (wrow + mi * 16 + c) * 64 + (((kk << 2) + q) ^ c7) * 8);
#pragma unroll
            for (int ni = 0; ni < 4; ++ni)
                bh[ni] = ldsld(Vs + (wcol + ni * 16 + c) * 64 + (((kk << 2) + q) ^ c7) * 8);
#pragma unroll
            for (int mi = 0; mi < 4; ++mi)
#pragma unroll
                for (int ni = 0; ni < 4; ++ni)
                    acc[mi][ni] = __builtin_amdgcn_mfma_f32_16x16x32_f16(ah[mi], bh[ni], acc[mi][ni], 0, 0, 0);
        }
    }
#pragma unroll
    for (int mi = 0; mi < 4; ++mi)
#pragma unroll
        for (int ni = 0; ni < 4; ++ni) {
            const int dcol = d0 + wcol + ni * 16 + c;
#pragma unroll
            for (int r = 0; r < 4; ++r) {
                const int i = i0 + wrow + mi * 16 + q * 4 + r;
                float* p = &Out[((size_t)b * SEQ + i) * DIM + dcol];
                if (useAtomic) atomicAdd(p, acc[mi][ni][r]);
                else *p = acc[mi][ni][r];
            }
        }
}

extern "C" void kernel_launch(void* const* d_in, const int* in_sizes, int n_in,
                              void* d_out, int out_size, void* d_ws, size_t ws_size,
                              hipStream_t stream)
{
    (void)out_size; (void)ws_size;
    const float* X = nullptr;
    const float* Wv[3] = {nullptr, nullptr, nullptr};
    int nw = 0;
    for (int i = 0; i < n_in; ++i) {
        if (in_sizes[i] == (int)NBS)
            X = (const float*)d_in[i];
        else if (nw < 3)
            Wv[nw++] = (const float*)d_in[i];
    }

    unsigned short* ws = (unsigned short*)d_ws;
    unsigned short* Qf = ws;                 // 16 MB
    unsigned short* Kf = ws + NBS;           // 16 MB
    unsigned short* Vt = ws + 2 * NBS;       // 16 MB
    unsigned short* Xf = ws + 3 * NBS;       // consumed by qkv gemm
    unsigned short* Pp = ws + 3 * NBS;       // P aliases Xf after qkv (32 MB)
    unsigned short* Sb = ws + 5 * NBS;       // fp16 S, all batches (32 MB)
    unsigned short* Wf = ws + 7 * NBS;       // 6 MB
    float* Out = (float*)d_out;

    cvt_all<<<dim3(8192 + 3072), 256, 0, stream>>>(X, Wv[0], Wv[1], Wv[2], Xf, Wf);

    qkv_gemm<<<dim3(1536), 256, 0, stream>>>(Xf, Wf, Qf, Kf, Vt);

    scores_gemm1b<<<dim3(16, 16, BATCH), 256, 0, stream>>>(Qf, Kf, Sb);
    softmax_row_b<<<dim3(SEQ, BATCH), 256, 0, stream>>>(Sb, Pp);

    // Zero Out for the split-K atomic region, then pv.
    hipMemsetAsync(d_out, 0, (size_t)BATCH * SEQ * DIM * sizeof(float), stream);
    pv_gemm<<<dim3(24, 8, BATCH), 256, 0, stream>>>(Pp, Vt, Out);
}

// Round 5
// 245.930 us; speedup vs baseline: 1.0296x; 1.0296x over previous
//
#include <hip/hip_runtime.h>

typedef _Float16 f16x8 __attribute__((ext_vector_type(8)));
typedef unsigned short u16x8v __attribute__((ext_vector_type(8)));
typedef unsigned short u16x4v __attribute__((ext_vector_type(4)));
typedef float f32x4 __attribute__((ext_vector_type(4)));

constexpr int SEQ = 2048;
constexpr int DIM = 1024;
constexpr int BATCH = 4;
constexpr size_t NBS = (size_t)BATCH * SEQ * DIM;  // 8388608

static __device__ __forceinline__ unsigned short f2h(float f) {
    return __builtin_bit_cast(unsigned short, (_Float16)f);  // RNE
}
static __device__ __forceinline__ float h2f(unsigned short u) {
    return (float)__builtin_bit_cast(_Float16, u);
}
static __device__ __forceinline__ f16x8 ldsld(const unsigned short* p) {
    return __builtin_bit_cast(f16x8, *(const u16x8v*)p);
}
// Async global->LDS, 16B/lane. LDS dest = wave-uniform base + lane*16B.
static __device__ __forceinline__ void gld_lds16(const unsigned short* g, unsigned short* l) {
    __builtin_amdgcn_global_load_lds(
        (const __attribute__((address_space(1))) void*)g,
        (__attribute__((address_space(3))) void*)l, 16, 0, 0);
}

// ---------------------------------------------------------------------------
// fp32 -> fp16 convert, X + all 3 W in ONE launch.
// Blocks [0,8192): X. Blocks [8192, 8192+3072): W0..W2.
// ---------------------------------------------------------------------------
__global__ __launch_bounds__(256) void cvt_all(
    const float* __restrict__ X,
    const float* __restrict__ W0, const float* __restrict__ W1,
    const float* __restrict__ W2,
    unsigned short* __restrict__ Xf, unsigned short* __restrict__ Wf)
{
    const int b = blockIdx.x;
    const float* src;
    unsigned short* dst;
    int i;
    if (b < 8192) {
        src = X; dst = Xf;
        i = b * 256 + threadIdx.x;
    } else {
        const int wb = b - 8192;
        const int z = wb >> 10;              // 1024 blocks per weight
        src = (z == 0) ? W0 : (z == 1) ? W1 : W2;
        dst = Wf + (size_t)z * DIM * DIM;
        i = (wb & 1023) * 256 + threadIdx.x;
    }
    float4 f = ((const float4*)src)[i];
    u16x4v h;
    h.x = f2h(f.x); h.y = f2h(f.y); h.z = f2h(f.z); h.w = f2h(f.w);
    ((u16x4v*)dst)[i] = h;
}

// ---------------------------------------------------------------------------
// Fused Q/K/V projection, fp16 MFMA. 128x128 tile, 4 waves x 64x64, BK=64,
// XOR-swizzled LDS (rule 21: linear gld_lds dest + inverse-swizzled global
// source + swizzled read). 2-D grid, m fastest (r3 layout: keeps the 256 KB
// W panel L2-hot per (n,z) sweep; X lives in L3). r4's XCD m-chunking
// thrashed W in L2 (FETCH 49->84 MB) -- do not reintroduce.
// ---------------------------------------------------------------------------
__global__ __launch_bounds__(256) void qkv_gemm(
    const unsigned short* __restrict__ Xf, const unsigned short* __restrict__ Wf,
    unsigned short* __restrict__ Qf, unsigned short* __restrict__ Kf,
    unsigned short* __restrict__ Vt)
{
    __shared__ __attribute__((aligned(16))) unsigned short Ah[128 * 64];
    __shared__ __attribute__((aligned(16))) unsigned short Bh[128 * 64];
    const int m0 = blockIdx.x * 128, n0 = blockIdx.y * 128, z = blockIdx.z;
    const unsigned short* Wz = Wf + (size_t)z * DIM * DIM;
    const int tid = threadIdx.x;
    const int w = tid >> 6, lane = tid & 63, q = lane >> 4, c = lane & 15;
    const int wrow = (w >> 1) * 64, wcol = (w & 1) * 64;
    const int g8 = lane >> 3;                 // row-in-group 0..7
    const int cu = (lane & 7) ^ g8;           // inverse-swizzled col unit
    const int srow = w * 8 + g8;              // staging row (call j adds j*32)
    const int scol = cu * 8;                  // shorts
    unsigned short* lA = Ah + w * 512;        // wave-uniform LDS bases
    unsigned short* lB = Bh + w * 512;
    const int c7 = c & 7;

    f32x4 acc[4][4];
#pragma unroll
    for (int a = 0; a < 4; ++a)
#pragma unroll
        for (int b = 0; b < 4; ++b) acc[a][b] = (f32x4){0.f, 0.f, 0.f, 0.f};

    for (int k0 = 0; k0 < DIM; k0 += 64) {
        __syncthreads();
        {
            const size_t ga = (size_t)(m0 + srow) * DIM + k0 + scol;
            const size_t gb = (size_t)(n0 + srow) * DIM + k0 + scol;
#pragma unroll
            for (int j = 0; j < 4; ++j) {
                gld_lds16(Xf + ga + (size_t)(j * 32) * DIM, lA + j * 2048);
                gld_lds16(Wz + gb + (size_t)(j * 32) * DIM, lB + j * 2048);
            }
        }
        __syncthreads();
#pragma unroll
        for (int kk = 0; kk < 2; ++kk) {
            f16x8 ah[4], bh[4];
#pragma unroll
            for (int mi = 0; mi < 4; ++mi)
                ah[mi] = ldsld(Ah + (wrow + mi * 16 + c) * 64 + (((kk << 2) + q) ^ c7) * 8);
#pragma unroll
            for (int ni = 0; ni < 4; ++ni)
                bh[ni] = ldsld(Bh + (wcol + ni * 16 + c) * 64 + (((kk << 2) + q) ^ c7) * 8);
#pragma unroll
            for (int mi = 0; mi < 4; ++mi)
#pragma unroll
                for (int ni = 0; ni < 4; ++ni)
                    acc[mi][ni] = __builtin_amdgcn_mfma_f32_16x16x32_f16(ah[mi], bh[ni], acc[mi][ni], 0, 0, 0);
        }
    }

    if (z == 2) {
        // V: store transposed Vt[b][d][s], fp16.
#pragma unroll
        for (int mi = 0; mi < 4; ++mi) {
            const int mg = m0 + wrow + mi * 16 + q * 4;
            const int bb = mg >> 11, ss = mg & (SEQ - 1);
#pragma unroll
            for (int ni = 0; ni < 4; ++ni) {
                const int col = n0 + wcol + ni * 16 + c;
                u16x4v v;
                v.x = f2h(acc[mi][ni][0]);
                v.y = f2h(acc[mi][ni][1]);
                v.z = f2h(acc[mi][ni][2]);
                v.w = f2h(acc[mi][ni][3]);
                *(u16x4v*)(Vt + ((size_t)bb * DIM + col) * SEQ + ss) = v;
            }
        }
    } else {
        unsigned short* OH = z ? Kf : Qf;
#pragma unroll
        for (int mi = 0; mi < 4; ++mi)
#pragma unroll
            for (int ni = 0; ni < 4; ++ni) {
                const int col = n0 + wcol + ni * 16 + c;
#pragma unroll
                for (int r = 0; r < 4; ++r) {
                    const int row = m0 + wrow + mi * 16 + q * 4 + r;
                    OH[(size_t)row * DIM + col] = f2h(acc[mi][ni][r]);
                }
            }
    }
}

// ---------------------------------------------------------------------------
// Scores GEMM, ALL batches: S = Qf Kf^T * SCALE, fp16 out. Faithful masking
// of scores==0 on the f32 accumulator: writes 0xFC00. Triangular-flattened
// grid: x = t in [0,136) -> (i >= j) tile via triangular inversion; no idle
// early-return blocks. BK=64 swizzled.
// ---------------------------------------------------------------------------
__global__ __launch_bounds__(256) void scores_gemm1b(
    const unsigned short* __restrict__ Q, const unsigned short* __restrict__ K,
    unsigned short* __restrict__ S)
{
    __shared__ __attribute__((aligned(16))) unsigned short Ah[128 * 64];
    __shared__ __attribute__((aligned(16))) unsigned short Bh[128 * 64];
    const int t = blockIdx.x;                  // 0..135
    int ti = (int)((__builtin_sqrtf(8.f * t + 1.f) - 1.f) * 0.5f);
    while ((ti + 1) * (ti + 2) / 2 <= t) ++ti;
    while (ti * (ti + 1) / 2 > t) --ti;
    const int tj = t - ti * (ti + 1) / 2;
    const int i0 = ti * 128, j0 = tj * 128, b = blockIdx.z;
    const unsigned short* Qb = Q + (size_t)b * SEQ * DIM;
    const unsigned short* Kb = K + (size_t)b * SEQ * DIM;
    unsigned short* Sb = S + (size_t)b * SEQ * SEQ;
    const int tid = threadIdx.x;
    const int w = tid >> 6, lane = tid & 63, q = lane >> 4, c = lane & 15;
    const int wrow = (w >> 1) * 64, wcol = (w & 1) * 64;
    const int g8 = lane >> 3;
    const int cu = (lane & 7) ^ g8;
    const int srow = w * 8 + g8;
    const int scol = cu * 8;
    unsigned short* lA = Ah + w * 512;
    unsigned short* lB = Bh + w * 512;
    const int c7 = c & 7;

    f32x4 acc[4][4];
#pragma unroll
    for (int a = 0; a < 4; ++a)
#pragma unroll
        for (int bq = 0; bq < 4; ++bq) acc[a][bq] = (f32x4){0.f, 0.f, 0.f, 0.f};

    for (int k0 = 0; k0 < DIM; k0 += 64) {
        __syncthreads();
        {
            const size_t ga = (size_t)(i0 + srow) * DIM + k0 + scol;
            const size_t gb = (size_t)(j0 + srow) * DIM + k0 + scol;
#pragma unroll
            for (int j = 0; j < 4; ++j) {
                gld_lds16(Qb + ga + (size_t)(j * 32) * DIM, lA + j * 2048);
                gld_lds16(Kb + gb + (size_t)(j * 32) * DIM, lB + j * 2048);
            }
        }
        __syncthreads();
#pragma unroll
        for (int kk = 0; kk < 2; ++kk) {
            f16x8 ah[4], bh[4];
#pragma unroll
            for (int mi = 0; mi < 4; ++mi)
                ah[mi] = ldsld(Ah + (wrow + mi * 16 + c) * 64 + (((kk << 2) + q) ^ c7) * 8);
#pragma unroll
            for (int ni = 0; ni < 4; ++ni)
                bh[ni] = ldsld(Bh + (wcol + ni * 16 + c) * 64 + (((kk << 2) + q) ^ c7) * 8);
#pragma unroll
            for (int mi = 0; mi < 4; ++mi)
#pragma unroll
                for (int ni = 0; ni < 4; ++ni)
                    acc[mi][ni] = __builtin_amdgcn_mfma_f32_16x16x32_f16(ah[mi], bh[ni], acc[mi][ni], 0, 0, 0);
        }
    }
#pragma unroll
    for (int mi = 0; mi < 4; ++mi)
#pragma unroll
        for (int ni = 0; ni < 4; ++ni) {
            const int col = j0 + wcol + ni * 16 + c;
#pragma unroll
            for (int r = 0; r < 4; ++r) {
                const int row = i0 + wrow + mi * 16 + q * 4 + r;
                const float sc = acc[mi][ni][r] * 0.03125f;
                Sb[(size_t)row * SEQ + col] =
                    (sc == 0.f) ? (unsigned short)0xFC00u : f2h(sc);
            }
        }
}

// ---------------------------------------------------------------------------
// Row-wise masked softmax: fp16 S -> fp16 P. j > i masked; scores==0 already
// -inf. Skip loads beyond i, skip writes beyond rowtile end. Grid (SEQ, BATCH).
// ---------------------------------------------------------------------------
__global__ __launch_bounds__(256) void softmax_row_b(
    const unsigned short* __restrict__ S, unsigned short* __restrict__ P)
{
    const int i = blockIdx.x, t = threadIdx.x;
    const size_t ro = ((size_t)blockIdx.y * SEQ + i) * SEQ;
    const int wid = t >> 6, lane = t & 63;
    __shared__ float redm[4], reds[4];
    const int j0 = t * 8;
    const int rti = (i & ~127) + 128;        // pv reads cols < rti only
    float sv[8];
    float mx = -__builtin_inff();
    if (j0 <= i) {
        u16x8v raw = *(const u16x8v*)(S + ro + j0);
#pragma unroll
        for (int u = 0; u < 8; ++u) {
            float s = (j0 + u <= i) ? h2f(raw[u]) : -__builtin_inff();
            sv[u] = s;
            mx = fmaxf(mx, s);
        }
    } else {
#pragma unroll
        for (int u = 0; u < 8; ++u) sv[u] = -__builtin_inff();
    }
#pragma unroll
    for (int off = 1; off < 64; off <<= 1) mx = fmaxf(mx, __shfl_xor(mx, off));
    if (lane == 0) redm[wid] = mx;
    __syncthreads();
    const float M = fmaxf(fmaxf(redm[0], redm[1]), fmaxf(redm[2], redm[3]));
    float sum = 0.f;
#pragma unroll
    for (int u = 0; u < 8; ++u) {
        float e = __expf(sv[u] - M);
        sv[u] = e;
        sum += e;
    }
#pragma unroll
    for (int off = 1; off < 64; off <<= 1) sum += __shfl_xor(sum, off);
    if (lane == 0) reds[wid] = sum;
    __syncthreads();
    const float rinv = 1.f / (reds[0] + reds[1] + reds[2] + reds[3]);
    if (j0 < rti) {
        u16x8v o;
#pragma unroll
        for (int u = 0; u < 8; ++u) o[u] = f2h(sv[u] * rinv);
        *(u16x8v*)(P + ro + j0) = o;
    }
}

// ---------------------------------------------------------------------------
// out = P @ V via Vt (NT MFMA, fp16), fp32 store. 128x128 tile, BK=64
// swizzled; k-loop truncated at causal bound. CU load balance via dispatch
// pairing: 512 blocks over 256 CUs -> bid and bid+256 share a CU (round-robin
// over 8 XCDs x 32 slots; +256 preserves both). bid+256 = same x, batch z+2.
// Mapping i0t = (z<2) ? x : 15-x puts one long + one complementary short
// tile on each CU: constant 34 K-steps/CU. No atomics, no extra traffic.
// ---------------------------------------------------------------------------
__global__ __launch_bounds__(256) void pv_gemm(
    const unsigned short* __restrict__ Pm, const unsigned short* __restrict__ Vt,
    float* __restrict__ Out)
{
    __shared__ __attribute__((aligned(16))) unsigned short Ps[128 * 64];
    __shared__ __attribute__((aligned(16))) unsigned short Vs[128 * 64];
    const int b = blockIdx.z;
    const int i0t = (b < 2) ? blockIdx.x : 15 - blockIdx.x;
    const int i0 = i0t * 128, d0 = blockIdx.y * 128;
    const int tid = threadIdx.x;
    const int w = tid >> 6, lane = tid & 63, q = lane >> 4, c = lane & 15;
    const int wrow = (w >> 1) * 64, wcol = (w & 1) * 64;
    const int g8 = lane >> 3;
    const int cu = (lane & 7) ^ g8;
    const int srow = w * 8 + g8;
    const int scol = cu * 8;
    unsigned short* lA = Ps + w * 512;
    unsigned short* lB = Vs + w * 512;
    const int c7 = c & 7;

    f32x4 acc[4][4];
#pragma unroll
    for (int a = 0; a < 4; ++a)
#pragma unroll
        for (int bq = 0; bq < 4; ++bq) acc[a][bq] = (f32x4){0.f, 0.f, 0.f, 0.f};

    const int njs = 2 * i0t + 2;  // covers cols < i0+128

    for (int ks = 0; ks < njs; ++ks) {
        const int j0 = ks * 64;
        __syncthreads();
        {
            const size_t gpa = ((size_t)b * SEQ + i0 + srow) * SEQ + j0 + scol;
            const size_t gva = ((size_t)b * DIM + d0 + srow) * SEQ + j0 + scol;
#pragma unroll
            for (int j = 0; j < 4; ++j) {
                gld_lds16(Pm + gpa + (size_t)(j * 32) * SEQ, lA + j * 2048);
                gld_lds16(Vt + gva + (size_t)(j * 32) * SEQ, lB + j * 2048);
            }
        }
        __syncthreads();
#pragma unroll
        for (int kk = 0; kk < 2; ++kk) {
            f16x8 ah[4], bh[4];
#pragma unroll
            for (int mi = 0; mi < 4; ++mi)
                ah[mi] = ldsld(Ps + (wrow + mi * 16 + c) * 64 + (((kk << 2) + q) ^ c7) * 8);
#pragma unroll
            for (int ni = 0; ni < 4; ++ni)
                bh[ni] = ldsld(Vs + (wcol + ni * 16 + c) * 64 + (((kk << 2) + q) ^ c7) * 8);
#pragma unroll
            for (int mi = 0; mi < 4; ++mi)
#pragma unroll
                for (int ni = 0; ni < 4; ++ni)
                    acc[mi][ni] = __builtin_amdgcn_mfma_f32_16x16x32_f16(ah[mi], bh[ni], acc[mi][ni], 0, 0, 0);
        }
    }
#pragma unroll
    for (int mi = 0; mi < 4; ++mi)
#pragma unroll
        for (int ni = 0; ni < 4; ++ni) {
            const int dcol = d0 + wcol + ni * 16 + c;
#pragma unroll
            for (int r = 0; r < 4; ++r) {
                const int i = i0 + wrow + mi * 16 + q * 4 + r;
                Out[((size_t)b * SEQ + i) * DIM + dcol] = acc[mi][ni][r];
            }
        }
}

extern "C" void kernel_launch(void* const* d_in, const int* in_sizes, int n_in,
                              void* d_out, int out_size, void* d_ws, size_t ws_size,
                              hipStream_t stream)
{
    (void)out_size; (void)ws_size;
    const float* X = nullptr;
    const float* Wv[3] = {nullptr, nullptr, nullptr};
    int nw = 0;
    for (int i = 0; i < n_in; ++i) {
        if (in_sizes[i] == (int)NBS)
            X = (const float*)d_in[i];
        else if (nw < 3)
            Wv[nw++] = (const float*)d_in[i];
    }

    unsigned short* ws = (unsigned short*)d_ws;
    unsigned short* Qf = ws;                 // 16 MB
    unsigned short* Kf = ws + NBS;           // 16 MB
    unsigned short* Vt = ws + 2 * NBS;       // 16 MB
    unsigned short* Xf = ws + 3 * NBS;       // consumed by qkv gemm
    unsigned short* Pp = ws + 3 * NBS;       // P aliases Xf after qkv (32 MB)
    unsigned short* Sb = ws + 5 * NBS;       // fp16 S, all batches (32 MB)
    unsigned short* Wf = ws + 7 * NBS;       // 6 MB
    float* Out = (float*)d_out;

    cvt_all<<<dim3(8192 + 3072), 256, 0, stream>>>(X, Wv[0], Wv[1], Wv[2], Xf, Wf);

    qkv_gemm<<<dim3(64, 8, 3), 256, 0, stream>>>(Xf, Wf, Qf, Kf, Vt);

    scores_gemm1b<<<dim3(136, 1, BATCH), 256, 0, stream>>>(Qf, Kf, Sb);
    softmax_row_b<<<dim3(SEQ, BATCH), 256, 0, stream>>>(Sb, Pp);

    pv_gemm<<<dim3(16, 8, BATCH), 256, 0, stream>>>(Pp, Vt, Out);
}